// Round 12
// baseline (127.216 us; speedup 1.0000x reference)
//
#include <hip/hip_runtime.h>
#include <math.h>

#define HID    2048
#define NROW   16384
#define NCOL   168
#define BM     64      // rows per block
#define KSTEPS 64      // 2048 / 32
#define NELEM  2112    // 33 chunks * 64 lanes (16B each) per K-step
#define BUFB   33792   // 33 KB per LDS B buffer (x3)
#define CPD    172     // sC row stride (f32)
#define NSLOT  16
#define NSTEP  8

typedef short short8 __attribute__((ext_vector_type(8)));
typedef float f32x4  __attribute__((ext_vector_type(4)));
typedef unsigned int u32x4 __attribute__((ext_vector_type(4)));

// counted waits — T4 primitive. volatile + memory clobber pins memory ops.
static __device__ __forceinline__ void wait_vm9() {
  asm volatile("s_waitcnt vmcnt(9)" ::: "memory");
}
static __device__ __forceinline__ void wait_vm0() {
  asm volatile("s_waitcnt vmcnt(0)" ::: "memory");
}

// [bf16(x1) : bf16(x0)] via v_perm_b32 (1 VALU op)
static __device__ __forceinline__ unsigned pack_hi(unsigned u0, unsigned u1) {
  return __builtin_amdgcn_perm(u1, u0, 0x07060302u);
}

// 3-way bf16 split (truncating; captures ~24 mantissa bits across planes)
struct Planes { u32x4 p1, p2, p3; };
static __device__ __forceinline__ Planes split8(const float* x) {
  Planes P;
  #pragma unroll
  for (int q = 0; q < 4; ++q) {
    float x0 = x[2*q], x1 = x[2*q+1];
    unsigned u0 = __float_as_uint(x0), u1 = __float_as_uint(x1);
    P.p1[q] = pack_hi(u0, u1);
    float r0 = x0 - __uint_as_float(u0 & 0xFFFF0000u);
    float r1 = x1 - __uint_as_float(u1 & 0xFFFF0000u);
    unsigned v0 = __float_as_uint(r0), v1 = __float_as_uint(r1);
    P.p2[q] = pack_hi(v0, v1);
    float s0 = r0 - __uint_as_float(v0 & 0xFFFF0000u);
    float s1 = r1 - __uint_as_float(v1 & 0xFFFF0000u);
    P.p3[q] = pack_hi(__float_as_uint(s0), __float_as_uint(s1));
  }
  return P;
}

static __device__ __forceinline__ void loadA8(const float* p, float* x) {
  f32x4 a = *(const f32x4*)p;
  f32x4 b = *(const f32x4*)(p + 4);
  x[0]=a[0]; x[1]=a[1]; x[2]=a[2]; x[3]=a[3];
  x[4]=b[0]; x[5]=b[1]; x[6]=b[2]; x[7]=b[3];
}

// non-temporal A load (nt bit): hidden allocates evict-first in L2/L3 so the
// 2.06 MB wsB panel stays L2-resident — R11's measured limiter was B restage
// missing the thrashed L2 and saturating the ~7-8 TB/s L3 link.
static __device__ __forceinline__ void loadA8_nt(const float* p, float* x) {
  f32x4 a = __builtin_nontemporal_load((const f32x4*)p);
  f32x4 b = __builtin_nontemporal_load((const f32x4*)(p + 4));
  x[0]=a[0]; x[1]=a[1]; x[2]=a[2]; x[3]=a[3];
  x[4]=b[0]; x[5]=b[1]; x[6]=b[2]; x[7]=b[3];
}

static __device__ __forceinline__ f32x4 mf(short8 a, short8 b, f32x4 c) {
  return __builtin_amdgcn_mfma_f32_16x16x32_bf16(a, b, c, 0, 0, 0);
}

// async global->LDS, 16B per lane; LDS dest = wave-uniform base + lane*16
static __device__ __forceinline__ void gld_lds16(const void* g, void* l) {
  __builtin_amdgcn_global_load_lds(
      (const __attribute__((address_space(1))) unsigned int*)g,
      (__attribute__((address_space(3))) unsigned int*)l, 16, 0, 0);
}

// ---------------------------------------------------------------------------
// Prep: split W (concat 168 rows, 11 col-chunks of 16, zero-pad 168..175)
// into 3 bf16 planes in MFMA-B fragment-lane order.
// chunk(kidx, nt, pl): lane l holds B[k=kidx*32+(l>>4)*8+j][col=nt*16+(l&15)]
// ws element index = kidx*2112 + (nt*3+pl)*64 + l   (16B each)
// ---------------------------------------------------------------------------
__global__ void prep_b(const float* __restrict__ Wi, const float* __restrict__ Wo,
                       const float* __restrict__ Wg, u32x4* __restrict__ wsB) {
  int bid  = blockIdx.x;          // 64 * 11 = 704
  int kidx = bid / 11;
  int nt   = bid - kidx * 11;
  int l    = threadIdx.x;         // 64
  int col  = nt * 16 + (l & 15);
  int k0   = kidx * 32 + (l >> 4) * 8;

  float x[8];
  if (col < NCOL) {
    const float* wr = (col < 32)  ? (Wi + (size_t)col * HID)
                    : (col < 160) ? (Wo + (size_t)(col - 32) * HID)
                                  : (Wg + (size_t)(col - 160) * HID);
    loadA8(wr + k0, x);
  } else {
    #pragma unroll
    for (int i = 0; i < 8; ++i) x[i] = 0.f;
  }
  Planes P = split8(x);
  size_t base = (size_t)kidx * NELEM + (nt * 3) * 64 + l;
  wsB[base]       = P.p1;
  wsB[base + 64]  = P.p2;
  wsB[base + 128] = P.p3;
}

// ---------------------------------------------------------------------------
// Main: 256 blocks x 512 thr (8 waves: 2 wm x 4 wn), BM=64, 1 block/CU.
// Triple-buffered shared B staging, ONE raw s_barrier per body (no vmcnt
// drain), counted vmcnt(9). The wm-pair splits its slice's 9 chunks 5/5
// (1-chunk overlap, same step + same bytes under barrier lock => safe).
//
// Safety proof per body t (after barrier):
//   (a) every wave passed its own vmcnt(9) => all of B(t) landed in buf[t%3]
//       (partner completion transmitted by the barrier);
//   (b) every wave finished body t-1 => buf[(t+2)%3] is a safe DMA target.
// Ledger: 9 VMEM/body/wave (5 B-DMA + 4 A); steady vmcnt(9); tail 9 -> 0.
// ONLY change vs R11 (passing): A loads are non-temporal.
// ---------------------------------------------------------------------------
__global__ __launch_bounds__(512, 2)
void dag_main(const float* __restrict__ hidden, const u32x4* __restrict__ wsB,
              const float* __restrict__ b_init, const float* __restrict__ b_op,
              const float* __restrict__ b_gate, float* __restrict__ out)
{
  __shared__ __align__(16) char smem[3 * BUFB];   // 101376 B (sC overlays)

  const int tid = threadIdx.x;
  const int l   = tid & 63;
  const int w   = tid >> 6;       // wave 0..7
  const int wn  = w & 3;          // col-slice: cols wn*48 + j*16
  const int wm  = w >> 2;         // row-band:  rows wm*32 + mt*16
  const int row0 = blockIdx.x * BM;
  const int r   = l & 15;
  const int kg  = l >> 4;

  // A: lane l covers rows row0 + wm*32 + mt*16 + r, k = t*32 + kg*8
  const float* ap0 = hidden + (size_t)(row0 + wm * 32 + r) * HID + kg * 8;
  const float* ap1 = ap0 + (size_t)16 * HID;

  // staging split: wm=0 stages chunks cb..cb+4 = 9wn..9wn+4;
  // wm=1 stages 9wn+4..9wn+8 (wn<3) or 28..32 (wn==3, 6 real chunks).
  const int cb = 9 * wn + (wm ? ((wn == 3) ? 1 : 4) : 0);
  const u32x4* gsrc[5];
  char* ldst[5];
  #pragma unroll
  for (int i = 0; i < 5; ++i) {
    gsrc[i] = wsB + (size_t)(cb + i) * 64 + l;   // per-lane global source
    ldst[i] = smem + (cb + i) * 1024;            // wave-uniform LDS dest
  }
  // B fragment read base: chunk (9wn + j*3 + pl), byte = chunk*1024 + l*16
  const char* brd0 = smem + (size_t)(9 * wn) * 1024 + (size_t)l * 16;

  f32x4 acc[2][3];
  const f32x4 zf = {0.f, 0.f, 0.f, 0.f};
  #pragma unroll
  for (int mt = 0; mt < 2; ++mt)
    #pragma unroll
    for (int j = 0; j < 3; ++j) acc[mt][j] = zf;

  float xa0[8], xa1[8], xb0[8], xb1[8];

#define STAGE(t_, sel_) do {                                                \
    _Pragma("unroll")                                                       \
    for (int i = 0; i < 5; ++i)                                             \
      gld_lds16(gsrc[i] + (size_t)NELEM * (t_), ldst[i] + (sel_) * BUFB);   \
  } while (0)

  // BODY(t): wait own 9 -> barrier -> ds_read B(t) from buf[p] ->
  //          DMA B(t+2) into buf[(p+2)%3] -> split A(t) -> load A(t+2)
  //          -> MFMA (compiler inserts fine-grained lgkmcnt for bf).
#define BODY(t_, p_, xc0_, xc1_, ISSUE_, LAST_) do {                        \
    if (LAST_) wait_vm0(); else wait_vm9();                                 \
    __builtin_amdgcn_sched_barrier(0);                                      \
    __builtin_amdgcn_s_barrier();                                           \
    __builtin_amdgcn_sched_barrier(0);                                      \
    const char* bb = brd0 + (p_) * BUFB;                                    \
    short8 bf[9];                                                           \
    _Pragma("unroll")                                                       \
    for (int i = 0; i < 9; ++i)                                             \
      if (wn != 3 || i < 6) bf[i] = *(const short8*)(bb + i * 1024);        \
    if (ISSUE_) STAGE((t_) + 2, ((p_) + 2) % 3);                            \
    Planes PA0 = split8(xc0_);                                              \
    Planes PA1 = split8(xc1_);                                              \
    if (ISSUE_) {                                                           \
      loadA8_nt(ap0 + ((t_) + 2) * 32, xc0_);                               \
      loadA8_nt(ap1 + ((t_) + 2) * 32, xc1_);                               \
    }                                                                       \
    short8 a0p1 = __builtin_bit_cast(short8, PA0.p1);                       \
    short8 a0p2 = __builtin_bit_cast(short8, PA0.p2);                       \
    short8 a0p3 = __builtin_bit_cast(short8, PA0.p3);                       \
    short8 a1p1 = __builtin_bit_cast(short8, PA1.p1);                       \
    short8 a1p2 = __builtin_bit_cast(short8, PA1.p2);                       \
    short8 a1p3 = __builtin_bit_cast(short8, PA1.p3);                       \
    __builtin_amdgcn_s_setprio(1);                                          \
    _Pragma("unroll")                                                       \
    for (int j = 0; j < 3; ++j) {                                           \
      if (wn == 3 && j == 2) continue;                                      \
      short8 b1 = bf[j * 3 + 0];                                            \
      short8 b2 = bf[j * 3 + 1];                                            \
      short8 b3 = bf[j * 3 + 2];                                            \
      {                                                                     \
        f32x4 c = acc[0][j];                                                \
        c = mf(a0p1, b1, c); c = mf(a0p1, b2, c); c = mf(a0p2, b1, c);      \
        c = mf(a0p1, b3, c); c = mf(a0p2, b2, c); c = mf(a0p3, b1, c);      \
        acc[0][j] = c;                                                      \
      }                                                                     \
      {                                                                     \
        f32x4 c = acc[1][j];                                                \
        c = mf(a1p1, b1, c); c = mf(a1p1, b2, c); c = mf(a1p2, b1, c);      \
        c = mf(a1p1, b3, c); c = mf(a1p2, b2, c); c = mf(a1p3, b1, c);      \
        acc[1][j] = c;                                                      \
      }                                                                     \
    }                                                                       \
    __builtin_amdgcn_s_setprio(0);                                          \
  } while (0)

  // prologue: [B(0):5, A(0):4] then [B(1):5, A(1):4] = 18 in flight
  STAGE(0, 0);
  loadA8_nt(ap0,      xa0);
  loadA8_nt(ap1,      xa1);
  STAGE(1, 1);
  loadA8_nt(ap0 + 32, xb0);
  loadA8_nt(ap1 + 32, xb1);

  // bodies 0..61 issue t+2; buffer cycle period 3, A-reg period 2 -> unroll 6
  for (int t = 0; t < 60; t += 6) {
    BODY(t + 0, 0, xa0, xa1, true, false);
    BODY(t + 1, 1, xb0, xb1, true, false);
    BODY(t + 2, 2, xa0, xa1, true, false);
    BODY(t + 3, 0, xb0, xb1, true, false);
    BODY(t + 4, 1, xa0, xa1, true, false);
    BODY(t + 5, 2, xb0, xb1, true, false);
  }
  BODY(60, 0, xa0, xa1, true,  false);   // stages B(62) -> buf2
  BODY(61, 1, xb0, xb1, true,  false);   // stages B(63) -> buf0
  BODY(62, 2, xa0, xa1, false, false);   // 18 in flight -> vm9 drains t=62's
  BODY(63, 0, xb0, xb1, false, true);    // vm0
#undef BODY
#undef STAGE

  // epilogue: acc -> sC (overlays LDS; everything drained)
  __syncthreads();
  float (*sC)[CPD] = (float(*)[CPD])smem;
  #pragma unroll
  for (int mt = 0; mt < 2; ++mt) {
    #pragma unroll
    for (int j = 0; j < 3; ++j) {
      int col = wn * 48 + j * 16 + r;
      if (col < NCOL) {
        int row = wm * 32 + mt * 16 + kg * 4;
        sC[row + 0][col] = acc[mt][j][0];
        sC[row + 1][col] = acc[mt][j][1];
        sC[row + 2][col] = acc[mt][j][2];
        sC[row + 3][col] = acc[mt][j][3];
      }
    }
  }
  __syncthreads();

  // per-row sequential DAG: one lane per row
  if (tid < BM) {
    const int rr = tid;
    float Vm[NSLOT], Vs[NSLOT];
    #pragma unroll
    for (int i = 0; i < NSLOT; ++i) {
      float mv = sC[rr][i]      + b_init[i];
      float sv = sC[rr][16 + i] + b_init[16 + i];
      Vm[i] = fabsf(mv);
      Vs[i] = tanhf(sv);
    }
    float G[NSTEP];
    #pragma unroll
    for (int s = 0; s < NSTEP; ++s) {
      float gr = sC[rr][160 + s] + b_gate[s];
      G[s] = 1.0f / (1.0f + expf(-gr));
    }
    #pragma unroll
    for (int s = 0; s < NSTEP; ++s) {
      const float g = G[s];
      float R = 0.f, sp = 1.f;
      #pragma unroll
      for (int i = 0; i < NSLOT; ++i) {
        float Osi = (i < 8 + s) ? (sC[rr][32 + s * 16 + i] + b_op[s * 16 + i]) : 0.f;
        float sgn   = Vs[i] * Vm[i];
        float logm  = logf(fmaxf(Vm[i], 1e-12f));
        float mixed = logm * (1.f - g) + sgn * g;
        R  += Osi * mixed;
        sp *= Vs[i] * (fabsf(Osi) + 1.f);
      }
      float lin_sign = tanhf(R  / 1e-4f);
      float log_sign = tanhf(sp / 1e-4f);
      float vs_new = g * lin_sign + (1.f - g) * log_sign;
      float vm_new = g * fabsf(R) + (1.f - g) * expf(fminf(R, 23.026f));
      Vm[8 + s] = vm_new;
      Vs[8 + s] = vs_new;
    }
    out[row0 + rr] = Vs[NSLOT - 1] * Vm[NSLOT - 1];
  }
}

extern "C" void kernel_launch(void* const* d_in, const int* in_sizes, int n_in,
                              void* d_out, int out_size, void* d_ws, size_t ws_size,
                              hipStream_t stream) {
  (void)in_sizes; (void)n_in; (void)out_size; (void)ws_size;
  const float* hidden = (const float*)d_in[0];
  const float* W_init = (const float*)d_in[1];
  const float* b_init = (const float*)d_in[2];
  const float* W_op   = (const float*)d_in[3];
  const float* b_op   = (const float*)d_in[4];
  const float* W_gate = (const float*)d_in[5];
  const float* b_gate = (const float*)d_in[6];
  float* out = (float*)d_out;
  u32x4* wsB = (u32x4*)d_ws;      // 64 * 2112 * 16 B = 2.06 MiB

  prep_b<<<dim3(704), dim3(64), 0, stream>>>(W_init, W_op, W_gate, wsB);
  dag_main<<<dim3(NROW / BM), dim3(512), 0, stream>>>(hidden, wsB, b_init, b_op,
                                                      b_gate, out);
}

// Round 13
// 100.465 us; speedup vs baseline: 1.2663x; 1.2663x over previous
//
#include <hip/hip_runtime.h>
#include <math.h>

#define HID    2048
#define NROW   16384
#define NCOL   168
#define BM     64      // rows per block
#define KSTEPS 64      // 2048 / 32
#define NSUP   32      // supersteps (2 K-steps each)
#define NELEM  2112    // 33 chunks * 64 lanes (16B each) per K-step
#define SLICE  33792   // bytes of B per K-step (33 KB)
#define SUPB   67584   // superstep buffer = 2 slices (x2 buffers = 132 KB)
#define CPD    172     // sC row stride (f32)
#define NSLOT  16
#define NSTEP  8

typedef short short8 __attribute__((ext_vector_type(8)));
typedef float f32x4  __attribute__((ext_vector_type(4)));
typedef unsigned int u32x4 __attribute__((ext_vector_type(4)));

// entry wait: drains the 10 B-DMAs of this superstep (oldest in queue);
// leaves the 8 A-loads + anything newer in flight. T4 primitive.
static __device__ __forceinline__ void wait_vm8() {
  asm volatile("s_waitcnt vmcnt(8)" ::: "memory");
}

// [bf16(x1) : bf16(x0)] via v_perm_b32 (1 VALU op)
static __device__ __forceinline__ unsigned pack_hi(unsigned u0, unsigned u1) {
  return __builtin_amdgcn_perm(u1, u0, 0x07060302u);
}

// 3-way bf16 split (truncating; captures ~24 mantissa bits across planes)
struct Planes { u32x4 p1, p2, p3; };
static __device__ __forceinline__ Planes split8(const float* x) {
  Planes P;
  #pragma unroll
  for (int q = 0; q < 4; ++q) {
    float x0 = x[2*q], x1 = x[2*q+1];
    unsigned u0 = __float_as_uint(x0), u1 = __float_as_uint(x1);
    P.p1[q] = pack_hi(u0, u1);
    float r0 = x0 - __uint_as_float(u0 & 0xFFFF0000u);
    float r1 = x1 - __uint_as_float(u1 & 0xFFFF0000u);
    unsigned v0 = __float_as_uint(r0), v1 = __float_as_uint(r1);
    P.p2[q] = pack_hi(v0, v1);
    float s0 = r0 - __uint_as_float(v0 & 0xFFFF0000u);
    float s1 = r1 - __uint_as_float(v1 & 0xFFFF0000u);
    P.p3[q] = pack_hi(__float_as_uint(s0), __float_as_uint(s1));
  }
  return P;
}

static __device__ __forceinline__ void loadA8(const float* p, float* x) {
  f32x4 a = *(const f32x4*)p;
  f32x4 b = *(const f32x4*)(p + 4);
  x[0]=a[0]; x[1]=a[1]; x[2]=a[2]; x[3]=a[3];
  x[4]=b[0]; x[5]=b[1]; x[6]=b[2]; x[7]=b[3];
}

static __device__ __forceinline__ f32x4 mf(short8 a, short8 b, f32x4 c) {
  return __builtin_amdgcn_mfma_f32_16x16x32_bf16(a, b, c, 0, 0, 0);
}

// async global->LDS, 16B per lane; LDS dest = wave-uniform base + lane*16
static __device__ __forceinline__ void gld_lds16(const void* g, void* l) {
  __builtin_amdgcn_global_load_lds(
      (const __attribute__((address_space(1))) unsigned int*)g,
      (__attribute__((address_space(3))) unsigned int*)l, 16, 0, 0);
}

// ---------------------------------------------------------------------------
// Prep: split W (concat 168 rows, 11 col-chunks of 16, zero-pad 168..175)
// into 3 bf16 planes in MFMA-B fragment-lane order.
// chunk(kidx, nt, pl): lane l holds B[k=kidx*32+(l>>4)*8+j][col=nt*16+(l&15)]
// ws element index = kidx*2112 + (nt*3+pl)*64 + l   (16B each)
// ---------------------------------------------------------------------------
__global__ void prep_b(const float* __restrict__ Wi, const float* __restrict__ Wo,
                       const float* __restrict__ Wg, u32x4* __restrict__ wsB) {
  int bid  = blockIdx.x;          // 64 * 11 = 704
  int kidx = bid / 11;
  int nt   = bid - kidx * 11;
  int l    = threadIdx.x;         // 64
  int col  = nt * 16 + (l & 15);
  int k0   = kidx * 32 + (l >> 4) * 8;

  float x[8];
  if (col < NCOL) {
    const float* wr = (col < 32)  ? (Wi + (size_t)col * HID)
                    : (col < 160) ? (Wo + (size_t)(col - 32) * HID)
                                  : (Wg + (size_t)(col - 160) * HID);
    loadA8(wr + k0, x);
  } else {
    #pragma unroll
    for (int i = 0; i < 8; ++i) x[i] = 0.f;
  }
  Planes P = split8(x);
  size_t base = (size_t)kidx * NELEM + (nt * 3) * 64 + l;
  wsB[base]       = P.p1;
  wsB[base + 64]  = P.p2;
  wsB[base + 128] = P.p3;
}

// ---------------------------------------------------------------------------
// Main: 256 blocks x 512 thr (8 waves: 2 wm x 4 wn), BM=64, 1 block/CU.
// SUPERSTEP structure: ONE vmcnt(8)+s_barrier per 2 K-steps (32 sync events
// vs R11's 64 — the single variable under test). Double-buffered 66 KB
// super-buffers; staging into buf p^1 after barrier(s) is safe because every
// wave passing barrier(s) has finished body s-1's reads of that buffer.
// Ledger per body per wave (issue order): B(s+1):10 DMA, A(2s+2):4,
// A(2s+3):4 = 18 in flight at next entry; vmcnt(8) drains exactly B(s+1).
// Mid-body A-register waits are compiler-auto (plain loads; R11-proven).
// ---------------------------------------------------------------------------
__global__ __launch_bounds__(512, 2)
void dag_main(const float* __restrict__ hidden, const u32x4* __restrict__ wsB,
              const float* __restrict__ b_init, const float* __restrict__ b_op,
              const float* __restrict__ b_gate, float* __restrict__ out)
{
  __shared__ __align__(16) char smem[2 * SUPB];   // 135168 B (sC overlays)

  const int tid = threadIdx.x;
  const int l   = tid & 63;
  const int w   = tid >> 6;       // wave 0..7
  const int wn  = w & 3;          // col-slice: cols wn*48 + j*16
  const int wm  = w >> 2;         // row-band:  rows wm*32 + mt*16
  const int row0 = blockIdx.x * BM;
  const int r   = l & 15;
  const int kg  = l >> 4;

  // A: lane l covers rows row0 + wm*32 + mt*16 + r, k = t*32 + kg*8
  const float* ap0 = hidden + (size_t)(row0 + wm * 32 + r) * HID + kg * 8;
  const float* ap1 = ap0 + (size_t)16 * HID;

  // staging split: wm=0 stages chunks 9wn..9wn+4; wm=1 stages 9wn+4..9wn+8
  // (wn==3: shifted by 1, idempotent overlap) — uniform 5 chunks/wave/slice.
  const int cb = 9 * wn + (wm ? ((wn == 3) ? 1 : 4) : 0);
  const u32x4* gsrc[5];
  char* ldst[5];
  #pragma unroll
  for (int i = 0; i < 5; ++i) {
    gsrc[i] = wsB + (size_t)(cb + i) * 64 + l;   // per-lane global source
    ldst[i] = smem + (cb + i) * 1024;            // wave-uniform LDS dest
  }
  // B fragment read base: chunk (9wn + j*3 + pl), byte = chunk*1024 + l*16
  const char* brd0 = smem + (size_t)(9 * wn) * 1024 + (size_t)l * 16;

  f32x4 acc[2][3];
  const f32x4 zf = {0.f, 0.f, 0.f, 0.f};
  #pragma unroll
  for (int mt = 0; mt < 2; ++mt)
    #pragma unroll
    for (int j = 0; j < 3; ++j) acc[mt][j] = zf;

  float xe0[8], xe1[8], xo0[8], xo1[8];   // A regs: even step / odd step sets

#define STAGE(s_, sel_) do {                                                 \
    _Pragma("unroll")                                                        \
    for (int q = 0; q < 2; ++q)                                              \
      _Pragma("unroll")                                                      \
      for (int i = 0; i < 5; ++i)                                            \
        gld_lds16(gsrc[i] + (size_t)NELEM * (2 * (s_) + q),                  \
                  ldst[i] + (sel_) * SUPB + q * SLICE);                      \
  } while (0)

  // one K-step's fragment reads + split + MFMA (bb_ = slice base in LDS)
#define KSTEP(bb_, xc0_, xc1_, ISSA_, t2_) do {                              \
    short8 bf[9];                                                            \
    _Pragma("unroll")                                                        \
    for (int i = 0; i < 9; ++i)                                              \
      if (wn != 3 || i < 6) bf[i] = *(const short8*)((bb_) + i * 1024);      \
    Planes PA0 = split8(xc0_);                                               \
    Planes PA1 = split8(xc1_);                                               \
    if (ISSA_) {                                                             \
      loadA8(ap0 + (t2_) * 32, xc0_);                                        \
      loadA8(ap1 + (t2_) * 32, xc1_);                                        \
    }                                                                        \
    short8 a0p1 = __builtin_bit_cast(short8, PA0.p1);                        \
    short8 a0p2 = __builtin_bit_cast(short8, PA0.p2);                        \
    short8 a0p3 = __builtin_bit_cast(short8, PA0.p3);                        \
    short8 a1p1 = __builtin_bit_cast(short8, PA1.p1);                        \
    short8 a1p2 = __builtin_bit_cast(short8, PA1.p2);                        \
    short8 a1p3 = __builtin_bit_cast(short8, PA1.p3);                        \
    __builtin_amdgcn_s_setprio(1);                                           \
    _Pragma("unroll")                                                        \
    for (int j = 0; j < 3; ++j) {                                            \
      if (wn == 3 && j == 2) continue;                                       \
      short8 b1 = bf[j * 3 + 0];                                             \
      short8 b2 = bf[j * 3 + 1];                                             \
      short8 b3 = bf[j * 3 + 2];                                             \
      {                                                                      \
        f32x4 c = acc[0][j];                                                 \
        c = mf(a0p1, b1, c); c = mf(a0p1, b2, c); c = mf(a0p2, b1, c);       \
        c = mf(a0p1, b3, c); c = mf(a0p2, b2, c); c = mf(a0p3, b1, c);       \
        acc[0][j] = c;                                                       \
      }                                                                      \
      {                                                                      \
        f32x4 c = acc[1][j];                                                 \
        c = mf(a1p1, b1, c); c = mf(a1p1, b2, c); c = mf(a1p2, b1, c);       \
        c = mf(a1p1, b3, c); c = mf(a1p2, b2, c); c = mf(a1p3, b1, c);       \
        acc[1][j] = c;                                                       \
      }                                                                      \
    }                                                                        \
    __builtin_amdgcn_s_setprio(0);                                           \
  } while (0)

  // BODY(s): vm8 -> barrier -> [stage B(s+1)] -> step 2s -> step 2s+1
#define BODY(s_, p_, ISSUE_) do {                                            \
    wait_vm8();                                                              \
    __builtin_amdgcn_sched_barrier(0);                                       \
    __builtin_amdgcn_s_barrier();                                            \
    __builtin_amdgcn_sched_barrier(0);                                       \
    if (ISSUE_) STAGE((s_) + 1, (p_) ^ 1);                                   \
    const char* be = brd0 + (p_) * SUPB;                                     \
    KSTEP(be,         xe0, xe1, (ISSUE_), 2 * (s_) + 2);                     \
    KSTEP(be + SLICE, xo0, xo1, (ISSUE_), 2 * (s_) + 3);                     \
  } while (0)

  // prologue: queue = [B(0):10, A(0):4, A(1):4] = 18 in flight
  STAGE(0, 0);
  loadA8(ap0,      xe0);
  loadA8(ap1,      xe1);
  loadA8(ap0 + 32, xo0);
  loadA8(ap1 + 32, xo1);

  for (int s = 0; s < 30; s += 2) {     // bodies 0..29 (p alternates 0/1)
    BODY(s,     0, true);
    BODY(s + 1, 1, true);
  }
  BODY(30, 0, true);                    // stages B(31) -> buf1
  BODY(31, 1, false);                   // reads buf1; nothing left to issue
#undef BODY
#undef KSTEP
#undef STAGE

  // epilogue: acc -> sC (overlays LDS; compiler drains all counters here)
  __syncthreads();
  float (*sC)[CPD] = (float(*)[CPD])smem;
  #pragma unroll
  for (int mt = 0; mt < 2; ++mt) {
    #pragma unroll
    for (int j = 0; j < 3; ++j) {
      int col = wn * 48 + j * 16 + r;
      if (col < NCOL) {
        int row = wm * 32 + mt * 16 + kg * 4;
        sC[row + 0][col] = acc[mt][j][0];
        sC[row + 1][col] = acc[mt][j][1];
        sC[row + 2][col] = acc[mt][j][2];
        sC[row + 3][col] = acc[mt][j][3];
      }
    }
  }
  __syncthreads();

  // per-row sequential DAG: one lane per row
  if (tid < BM) {
    const int rr = tid;
    float Vm[NSLOT], Vs[NSLOT];
    #pragma unroll
    for (int i = 0; i < NSLOT; ++i) {
      float mv = sC[rr][i]      + b_init[i];
      float sv = sC[rr][16 + i] + b_init[16 + i];
      Vm[i] = fabsf(mv);
      Vs[i] = tanhf(sv);
    }
    float G[NSTEP];
    #pragma unroll
    for (int s = 0; s < NSTEP; ++s) {
      float gr = sC[rr][160 + s] + b_gate[s];
      G[s] = 1.0f / (1.0f + expf(-gr));
    }
    #pragma unroll
    for (int s = 0; s < NSTEP; ++s) {
      const float g = G[s];
      float R = 0.f, sp = 1.f;
      #pragma unroll
      for (int i = 0; i < NSLOT; ++i) {
        float Osi = (i < 8 + s) ? (sC[rr][32 + s * 16 + i] + b_op[s * 16 + i]) : 0.f;
        float sgn   = Vs[i] * Vm[i];
        float logm  = logf(fmaxf(Vm[i], 1e-12f));
        float mixed = logm * (1.f - g) + sgn * g;
        R  += Osi * mixed;
        sp *= Vs[i] * (fabsf(Osi) + 1.f);
      }
      float lin_sign = tanhf(R  / 1e-4f);
      float log_sign = tanhf(sp / 1e-4f);
      float vs_new = g * lin_sign + (1.f - g) * log_sign;
      float vm_new = g * fabsf(R) + (1.f - g) * expf(fminf(R, 23.026f));
      Vm[8 + s] = vm_new;
      Vs[8 + s] = vs_new;
    }
    out[row0 + rr] = Vs[NSLOT - 1] * Vm[NSLOT - 1];
  }
}

extern "C" void kernel_launch(void* const* d_in, const int* in_sizes, int n_in,
                              void* d_out, int out_size, void* d_ws, size_t ws_size,
                              hipStream_t stream) {
  (void)in_sizes; (void)n_in; (void)out_size; (void)ws_size;
  const float* hidden = (const float*)d_in[0];
  const float* W_init = (const float*)d_in[1];
  const float* b_init = (const float*)d_in[2];
  const float* W_op   = (const float*)d_in[3];
  const float* b_op   = (const float*)d_in[4];
  const float* W_gate = (const float*)d_in[5];
  const float* b_gate = (const float*)d_in[6];
  float* out = (float*)d_out;
  u32x4* wsB = (u32x4*)d_ws;      // 64 * 2112 * 16 B = 2.06 MiB

  prep_b<<<dim3(704), dim3(64), 0, stream>>>(W_init, W_op, W_gate, wsB);
  dag_main<<<dim3(NROW / BM), dim3(512), 0, stream>>>(hidden, wsB, b_init, b_op,
                                                      b_gate, out);
}

// Round 14
// 100.132 us; speedup vs baseline: 1.2705x; 1.0033x over previous
//
#include <hip/hip_runtime.h>
#include <math.h>

#define HID    2048
#define NROW   16384
#define NCOL   168
#define BM     64      // rows per block
#define KSTEPS 64      // 2048 / 32
#define NELEM  2112    // 33 chunks * 64 lanes (16B each) per K-step
#define SLICE  33792   // bytes of B per K-step (33 KB)
#define SUPB   67584   // superstep buffer = 2 slices (x2 buffers = 132 KB)
#define CPD    172     // sC row stride (f32)
#define NSLOT  16
#define NSTEP  8

typedef short short8 __attribute__((ext_vector_type(8)));
typedef float f32x4  __attribute__((ext_vector_type(4)));
typedef unsigned int u32x4 __attribute__((ext_vector_type(4)));

// entry wait: leaves exactly this body's 4 A-instrs in flight; drains all of
// this superstep's B DMAs (count-independent of per-wave DMA share). T4.
static __device__ __forceinline__ void wait_vm4() {
  asm volatile("s_waitcnt vmcnt(4)" ::: "memory");
}

// [bf16(x1) : bf16(x0)] via v_perm_b32 (1 VALU op)
static __device__ __forceinline__ unsigned pack_hi(unsigned u0, unsigned u1) {
  return __builtin_amdgcn_perm(u1, u0, 0x07060302u);
}

// 3-way bf16 split (truncating; captures ~24 mantissa bits across planes)
struct Planes { u32x4 p1, p2, p3; };
static __device__ __forceinline__ Planes split8(const float* x) {
  Planes P;
  #pragma unroll
  for (int q = 0; q < 4; ++q) {
    float x0 = x[2*q], x1 = x[2*q+1];
    unsigned u0 = __float_as_uint(x0), u1 = __float_as_uint(x1);
    P.p1[q] = pack_hi(u0, u1);
    float r0 = x0 - __uint_as_float(u0 & 0xFFFF0000u);
    float r1 = x1 - __uint_as_float(u1 & 0xFFFF0000u);
    unsigned v0 = __float_as_uint(r0), v1 = __float_as_uint(r1);
    P.p2[q] = pack_hi(v0, v1);
    float s0 = r0 - __uint_as_float(v0 & 0xFFFF0000u);
    float s1 = r1 - __uint_as_float(v1 & 0xFFFF0000u);
    P.p3[q] = pack_hi(__float_as_uint(s0), __float_as_uint(s1));
  }
  return P;
}

static __device__ __forceinline__ void loadA8(const float* p, float* x) {
  f32x4 a = *(const f32x4*)p;
  f32x4 b = *(const f32x4*)(p + 4);
  x[0]=a[0]; x[1]=a[1]; x[2]=a[2]; x[3]=a[3];
  x[4]=b[0]; x[5]=b[1]; x[6]=b[2]; x[7]=b[3];
}

static __device__ __forceinline__ f32x4 mf(short8 a, short8 b, f32x4 c) {
  return __builtin_amdgcn_mfma_f32_16x16x32_bf16(a, b, c, 0, 0, 0);
}

// async global->LDS, 16B per lane; LDS dest = wave-uniform base + lane*16
static __device__ __forceinline__ void gld_lds16(const void* g, void* l) {
  __builtin_amdgcn_global_load_lds(
      (const __attribute__((address_space(1))) unsigned int*)g,
      (__attribute__((address_space(3))) unsigned int*)l, 16, 0, 0);
}

// ---------------------------------------------------------------------------
// Prep: split W (concat 168 rows, 11 col-chunks of 16, zero-pad 168..175)
// into 3 bf16 planes in MFMA-B fragment-lane order.
// chunk(kidx, nt, pl): lane l holds B[k=kidx*32+(l>>4)*8+j][col=nt*16+(l&15)]
// ws element index = kidx*2112 + (nt*3+pl)*64 + l   (16B each)
// ---------------------------------------------------------------------------
__global__ void prep_b(const float* __restrict__ Wi, const float* __restrict__ Wo,
                       const float* __restrict__ Wg, u32x4* __restrict__ wsB) {
  int bid  = blockIdx.x;          // 64 * 11 = 704
  int kidx = bid / 11;
  int nt   = bid - kidx * 11;
  int l    = threadIdx.x;         // 64
  int col  = nt * 16 + (l & 15);
  int k0   = kidx * 32 + (l >> 4) * 8;

  float x[8];
  if (col < NCOL) {
    const float* wr = (col < 32)  ? (Wi + (size_t)col * HID)
                    : (col < 160) ? (Wo + (size_t)(col - 32) * HID)
                                  : (Wg + (size_t)(col - 160) * HID);
    loadA8(wr + k0, x);
  } else {
    #pragma unroll
    for (int i = 0; i < 8; ++i) x[i] = 0.f;
  }
  Planes P = split8(x);
  size_t base = (size_t)kidx * NELEM + (nt * 3) * 64 + l;
  wsB[base]       = P.p1;
  wsB[base + 64]  = P.p2;
  wsB[base + 128] = P.p3;
}

// ---------------------------------------------------------------------------
// Main: 256 blocks x 1024 thr (16 waves: 4 wm x 4 wn), BM=64, 1 block/CU,
// 4 WAVES/SIMD (was 2 in every prior round — the variable under test).
// Wave tile 16 rows x 48 cols: per wave/K-step 1 loadA8, 1 split8, 18 MFMA.
// Superstep (2 K-steps) double buffer, one vmcnt(4)+s_barrier per superstep.
// Staging: wm-quad splits each wn-slice's 9 chunks {3,2,2,2}; ledger's entry
// wait vmcnt(4) = per-body A-instr count, independent of per-wave DMA share.
// Total MFMA / VALU / B-traffic unchanged vs R13; phases now decorrelate.
// ---------------------------------------------------------------------------
__global__ __launch_bounds__(1024, 1)
void dag_main(const float* __restrict__ hidden, const u32x4* __restrict__ wsB,
              const float* __restrict__ b_init, const float* __restrict__ b_op,
              const float* __restrict__ b_gate, float* __restrict__ out)
{
  __shared__ __align__(16) char smem[2 * SUPB];   // 135168 B (sC overlays)

  const int tid = threadIdx.x;
  const int l   = tid & 63;
  const int w   = tid >> 6;       // wave 0..15
  const int wn  = w & 3;          // col-slice: cols wn*48 + j*16
  const int wm  = w >> 2;         // row-band:  rows wm*16 + r (wm 0..3)
  const int row0 = blockIdx.x * BM;
  const int r   = l & 15;
  const int kg  = l >> 4;

  // A: lane l covers row row0 + wm*16 + r, k = t*32 + kg*8  (1 loadA8/K-step)
  const float* ap = hidden + (size_t)(row0 + wm * 16 + r) * HID + kg * 8;

  // staging split within slice wn: wm0 -> chunks {0,1,2}, wm1 -> {3,4},
  // wm2 -> {5,6}, wm3 -> {7,8}. For wn==3 (6 real chunks) indices >=6 wrap
  // to 0..2 (idempotent duplicate bytes, same superstep, barrier-locked).
  const int D  = (wm == 0) ? 3 : 2;          // DMAs per K-step (wave-uniform)
  const int s0 = (wm == 0) ? 0 : 2 * wm + 1; // start chunk within slice
  const u32x4* gsrc[3];
  char* ldst[3];
  #pragma unroll
  for (int i = 0; i < 3; ++i) {
    int ci = s0 + i; if (ci > 8) ci = 8;
    int cp = (wn == 3 && ci >= 6) ? ci - 6 : ci;
    int c  = 9 * wn + cp;
    gsrc[i] = wsB + (size_t)c * 64 + l;      // per-lane global source
    ldst[i] = smem + c * 1024;               // wave-uniform LDS dest
  }
  // B fragment read base: chunk (9wn + j*3 + pl), byte = chunk*1024 + l*16
  const char* brd0 = smem + (size_t)(9 * wn) * 1024 + (size_t)l * 16;

  f32x4 acc[3];
  const f32x4 zf = {0.f, 0.f, 0.f, 0.f};
  #pragma unroll
  for (int j = 0; j < 3; ++j) acc[j] = zf;

  float xe[8], xo[8];   // A regs: even-step / odd-step

#define STAGE(s_, sel_) do {                                                 \
    _Pragma("unroll")                                                        \
    for (int q = 0; q < 2; ++q)                                              \
      _Pragma("unroll")                                                      \
      for (int i = 0; i < 3; ++i)                                            \
        if (i < D)                                                           \
          gld_lds16(gsrc[i] + (size_t)NELEM * (2 * (s_) + q),                \
                    ldst[i] + (sel_) * SUPB + q * SLICE);                    \
  } while (0)

  // one K-step: per-j {3 ds_read_b128 -> 6 MFMA}; split + A-prefetch first
#define KSTEP(bb_, xc_, ISSA_, t2_) do {                                     \
    Planes PA = split8(xc_);                                                 \
    if (ISSA_) loadA8(ap + (t2_) * 32, xc_);                                 \
    short8 ap1 = __builtin_bit_cast(short8, PA.p1);                          \
    short8 ap2 = __builtin_bit_cast(short8, PA.p2);                          \
    short8 ap3 = __builtin_bit_cast(short8, PA.p3);                          \
    __builtin_amdgcn_s_setprio(1);                                           \
    _Pragma("unroll")                                                        \
    for (int j = 0; j < 3; ++j) {                                            \
      if (wn == 3 && j == 2) continue;                                       \
      short8 b1 = *(const short8*)((bb_) + (j * 3 + 0) * 1024);              \
      short8 b2 = *(const short8*)((bb_) + (j * 3 + 1) * 1024);              \
      short8 b3 = *(const short8*)((bb_) + (j * 3 + 2) * 1024);              \
      f32x4 c = acc[j];                                                      \
      c = mf(ap1, b1, c); c = mf(ap1, b2, c); c = mf(ap2, b1, c);            \
      c = mf(ap1, b3, c); c = mf(ap2, b2, c); c = mf(ap3, b1, c);            \
      acc[j] = c;                                                            \
    }                                                                        \
    __builtin_amdgcn_s_setprio(0);                                           \
  } while (0)

  // BODY(s): vm4 -> barrier -> [stage B(s+1)] -> step 2s -> step 2s+1
#define BODY(s_, p_, ISSUE_) do {                                            \
    wait_vm4();                                                              \
    __builtin_amdgcn_sched_barrier(0);                                       \
    __builtin_amdgcn_s_barrier();                                            \
    __builtin_amdgcn_sched_barrier(0);                                       \
    if (ISSUE_) STAGE((s_) + 1, (p_) ^ 1);                                   \
    const char* be = brd0 + (p_) * SUPB;                                     \
    KSTEP(be,         xe, (ISSUE_), 2 * (s_) + 2);                           \
    KSTEP(be + SLICE, xo, (ISSUE_), 2 * (s_) + 3);                           \
  } while (0)

  // prologue: queue = [B(0): 2D, A(0):2, A(1):2]; body-0 vm4 drains B(0)
  STAGE(0, 0);
  loadA8(ap,      xe);
  loadA8(ap + 32, xo);

  for (int s = 0; s < 30; s += 2) {     // bodies 0..29 (p alternates 0/1)
    BODY(s,     0, true);
    BODY(s + 1, 1, true);
  }
  BODY(30, 0, true);                    // stages B(31) -> buf1
  BODY(31, 1, false);                   // reads buf1; nothing left to issue
#undef BODY
#undef KSTEP
#undef STAGE

  // epilogue: acc -> sC (overlays LDS; all waves synced first)
  __syncthreads();
  float (*sC)[CPD] = (float(*)[CPD])smem;
  #pragma unroll
  for (int j = 0; j < 3; ++j) {
    int col = wn * 48 + j * 16 + r;
    if (col < NCOL) {
      int row = wm * 16 + kg * 4;
      sC[row + 0][col] = acc[j][0];
      sC[row + 1][col] = acc[j][1];
      sC[row + 2][col] = acc[j][2];
      sC[row + 3][col] = acc[j][3];
    }
  }
  __syncthreads();

  // per-row sequential DAG: one lane per row (wave 0)
  if (tid < BM) {
    const int rr = tid;
    float Vm[NSLOT], Vs[NSLOT];
    #pragma unroll
    for (int i = 0; i < NSLOT; ++i) {
      float mv = sC[rr][i]      + b_init[i];
      float sv = sC[rr][16 + i] + b_init[16 + i];
      Vm[i] = fabsf(mv);
      Vs[i] = tanhf(sv);
    }
    float G[NSTEP];
    #pragma unroll
    for (int s = 0; s < NSTEP; ++s) {
      float gr = sC[rr][160 + s] + b_gate[s];
      G[s] = 1.0f / (1.0f + expf(-gr));
    }
    #pragma unroll
    for (int s = 0; s < NSTEP; ++s) {
      const float g = G[s];
      float R = 0.f, sp = 1.f;
      #pragma unroll
      for (int i = 0; i < NSLOT; ++i) {
        float Osi = (i < 8 + s) ? (sC[rr][32 + s * 16 + i] + b_op[s * 16 + i]) : 0.f;
        float sgn   = Vs[i] * Vm[i];
        float logm  = logf(fmaxf(Vm[i], 1e-12f));
        float mixed = logm * (1.f - g) + sgn * g;
        R  += Osi * mixed;
        sp *= Vs[i] * (fabsf(Osi) + 1.f);
      }
      float lin_sign = tanhf(R  / 1e-4f);
      float log_sign = tanhf(sp / 1e-4f);
      float vs_new = g * lin_sign + (1.f - g) * log_sign;
      float vm_new = g * fabsf(R) + (1.f - g) * expf(fminf(R, 23.026f));
      Vm[8 + s] = vm_new;
      Vs[8 + s] = vs_new;
    }
    out[row0 + rr] = Vs[NSLOT - 1] * Vm[NSLOT - 1];
  }
}

extern "C" void kernel_launch(void* const* d_in, const int* in_sizes, int n_in,
                              void* d_out, int out_size, void* d_ws, size_t ws_size,
                              hipStream_t stream) {
  (void)in_sizes; (void)n_in; (void)out_size; (void)ws_size;
  const float* hidden = (const float*)d_in[0];
  const float* W_init = (const float*)d_in[1];
  const float* b_init = (const float*)d_in[2];
  const float* W_op   = (const float*)d_in[3];
  const float* b_op   = (const float*)d_in[4];
  const float* W_gate = (const float*)d_in[5];
  const float* b_gate = (const float*)d_in[6];
  float* out = (float*)d_out;
  u32x4* wsB = (u32x4*)d_ws;      // 64 * 2112 * 16 B = 2.06 MiB

  prep_b<<<dim3(704), dim3(64), 0, stream>>>(W_init, W_op, W_gate, wsB);
  dag_main<<<dim3(NROW / BM), dim3(1024), 0, stream>>>(hidden, wsB, b_init, b_op,
                                                       b_gate, out);
}